// Round 2
// baseline (83.134 us; speedup 1.0000x reference)
//
#include <hip/hip_runtime.h>
#include <math.h>

// Dims
#define D 2048
#define NH 8
#define NKV 2
#define HD 256
#define DFF 8192
#define W 512
#define PLD 256
#define EPS 1e-6f

__device__ __forceinline__ float warp_sum(float v) {
    #pragma unroll
    for (int off = 32; off > 0; off >>= 1) v += __shfl_down(v, off, 64);
    return v;
}
__device__ __forceinline__ float warp_max(float v) {
    #pragma unroll
    for (int off = 32; off > 0; off >>= 1) v = fmaxf(v, __shfl_down(v, off, 64));
    return v;
}

// block of 256 threads = 4 waves
__device__ __forceinline__ float block_sum256(float v, float* s4) {
    int lane = threadIdx.x & 63, wid = threadIdx.x >> 6;
    v = warp_sum(v);
    if (lane == 0) s4[wid] = v;
    __syncthreads();
    float r = s4[0] + s4[1] + s4[2] + s4[3];
    __syncthreads();
    return r;
}
__device__ __forceinline__ float block_max256(float v, float* s4) {
    int lane = threadIdx.x & 63, wid = threadIdx.x >> 6;
    v = warp_max(v);
    if (lane == 0) s4[wid] = v;
    __syncthreads();
    float r = fmaxf(fmaxf(s4[0], s4[1]), fmaxf(s4[2], s4[3]));
    __syncthreads();
    return r;
}

__device__ __forceinline__ float gelu_tanh(float x) {
    const float c = 0.7978845608028654f; // sqrt(2/pi)
    float t = tanhf(c * (x + 0.044715f * x * x * x));
    return 0.5f * x * (1.0f + t);
}

// async global -> LDS, 16 B per lane (1 KB per wave instruction, 0 VGPR held)
__device__ __forceinline__ void stage16(const float* g, float* l) {
    __builtin_amdgcn_global_load_lds((const __attribute__((address_space(1))) void*)g,
                                     (__attribute__((address_space(3))) void*)l, 16, 0, 0);
}

// ---------- h = rmsnorm(x, w) over D, 1 block x 256 ----------
__global__ void rms_in_kernel(const float* __restrict__ x, const float* __restrict__ w,
                              float* __restrict__ out) {
    __shared__ float s4[4];
    int t = threadIdx.x;
    float v[8], ss = 0.f;
    #pragma unroll
    for (int i = 0; i < 8; i++) { v[i] = x[t + i * 256]; ss += v[i] * v[i]; }
    float tot = block_sum256(ss, s4);
    float rs = rsqrtf(tot / (float)D + EPS);
    #pragma unroll
    for (int i = 0; i < 8; i++) out[t + i * 256] = v[i] * rs * (1.f + w[t + i * 256]);
}

// ---------- fused q/k/v projection via LDS staging: 3072 rows x 2048 ----------
// wave-per-row, full-row stage (8 KB/wave), no barriers.
__global__ void gemv_qkv_lds(const float* __restrict__ Wq, const float* __restrict__ Wk,
                             const float* __restrict__ Wv, const float* __restrict__ h,
                             float* __restrict__ qraw, float* __restrict__ kraw,
                             float* __restrict__ vraw) {
    __shared__ float smem[4 * 2048]; // 32 KB
    int lane = threadIdx.x & 63, wid = threadIdx.x >> 6;
    int row = blockIdx.x * 4 + wid; // 0..3071
    float* buf = smem + wid * 2048;
    const float* wr;
    float* out;
    if (row < 2048)      { wr = Wq + (size_t)row * D;          out = qraw + row; }
    else if (row < 2560) { wr = Wk + (size_t)(row - 2048) * D; out = kraw + (row - 2048); }
    else                 { wr = Wv + (size_t)(row - 2560) * D; out = vraw + (row - 2560); }
    #pragma unroll
    for (int c = 0; c < 8; c++) stage16(wr + c * 256 + lane * 4, buf + c * 256);
    float4 xv[8];
    #pragma unroll
    for (int c = 0; c < 8; c++) xv[c] = *reinterpret_cast<const float4*>(h + c * 256 + lane * 4);
    asm volatile("s_waitcnt vmcnt(0)" ::: "memory");
    float acc = 0.f;
    #pragma unroll
    for (int c = 0; c < 8; c++) {
        float4 wv = *reinterpret_cast<float4*>(buf + c * 256 + lane * 4);
        acc = fmaf(wv.x, xv[c].x, fmaf(wv.y, xv[c].y, fmaf(wv.z, xv[c].z, fmaf(wv.w, xv[c].w, acc))));
    }
    acc = warp_sum(acc);
    if (lane == 0) *out = acc;
}

// ---------- generic 2048-col GEMV via LDS staging ----------
// MODE 0: y[row] = acc      MODE 1: y[row] = gelu(acc) * aux[row]
template <int MODE>
__global__ void gemv2048_lds(const float* __restrict__ Wm, const float* __restrict__ x,
                             const float* __restrict__ aux, float* __restrict__ y) {
    __shared__ float smem[4 * 2048]; // 32 KB
    int lane = threadIdx.x & 63, wid = threadIdx.x >> 6;
    int row = blockIdx.x * 4 + wid;
    float* buf = smem + wid * 2048;
    const float* wr = Wm + (size_t)row * D;
    #pragma unroll
    for (int c = 0; c < 8; c++) stage16(wr + c * 256 + lane * 4, buf + c * 256);
    float4 xv[8];
    #pragma unroll
    for (int c = 0; c < 8; c++) xv[c] = *reinterpret_cast<const float4*>(x + c * 256 + lane * 4);
    asm volatile("s_waitcnt vmcnt(0)" ::: "memory");
    float acc = 0.f;
    #pragma unroll
    for (int c = 0; c < 8; c++) {
        float4 wv = *reinterpret_cast<float4*>(buf + c * 256 + lane * 4);
        acc = fmaf(wv.x, xv[c].x, fmaf(wv.y, xv[c].y, fmaf(wv.z, xv[c].z, fmaf(wv.w, xv[c].w, acc))));
    }
    acc = warp_sum(acc);
    if (lane == 0) {
        if (MODE == 0) y[row] = acc;
        else           y[row] = gelu_tanh(acc) * aux[row];
    }
}

// ---------- fused gate/up GEMV, double-buffered quarter sections ----------
// wave = row-pair. Per section: 2 gate chunks + 2 up chunks (4 KB). A/B buffers.
__global__ void gateup_lds(const float* __restrict__ Wg, const float* __restrict__ Wu,
                           const float* __restrict__ hn, float* __restrict__ act) {
    __shared__ float smem[4 * 2048]; // 8 KB/wave: A(1024 floats) + B(1024 floats)
    int lane = threadIdx.x & 63, wid = threadIdx.x >> 6;
    int row = blockIdx.x * 4 + wid; // 0..8191
    float* bufA = smem + wid * 2048;       // [0..511]=gate, [512..1023]=up
    float* bufB = bufA + 1024;
    const float* wg = Wg + (size_t)row * D;
    const float* wu = Wu + (size_t)row * D;
    // preload x (L1/L2-hit broadcast)
    float4 xv[8];
    #pragma unroll
    for (int c = 0; c < 8; c++) xv[c] = *reinterpret_cast<const float4*>(hn + c * 256 + lane * 4);
    // S0 -> A, S1 -> B   (each section: g chunks 2s,2s+1 and u chunks 2s,2s+1)
    #pragma unroll
    for (int i = 0; i < 2; i++) stage16(wg + (0 + i) * 256 + lane * 4, bufA + i * 256);
    #pragma unroll
    for (int i = 0; i < 2; i++) stage16(wu + (0 + i) * 256 + lane * 4, bufA + 512 + i * 256);
    #pragma unroll
    for (int i = 0; i < 2; i++) stage16(wg + (2 + i) * 256 + lane * 4, bufB + i * 256);
    #pragma unroll
    for (int i = 0; i < 2; i++) stage16(wu + (2 + i) * 256 + lane * 4, bufB + 512 + i * 256);
    float ag = 0.f, au = 0.f;
    // ---- section 0 (A); prefetch section 2 into A afterwards
    asm volatile("s_waitcnt vmcnt(4)" ::: "memory"); // X + S0 done, S1 outstanding
    #pragma unroll
    for (int i = 0; i < 2; i++) {
        float4 gv = *reinterpret_cast<float4*>(bufA + i * 256 + lane * 4);
        float4 uv = *reinterpret_cast<float4*>(bufA + 512 + i * 256 + lane * 4);
        float4 x4 = xv[0 * 2 + i];
        ag = fmaf(gv.x, x4.x, fmaf(gv.y, x4.y, fmaf(gv.z, x4.z, fmaf(gv.w, x4.w, ag))));
        au = fmaf(uv.x, x4.x, fmaf(uv.y, x4.y, fmaf(uv.z, x4.z, fmaf(uv.w, x4.w, au))));
    }
    #pragma unroll
    for (int i = 0; i < 2; i++) stage16(wg + (4 + i) * 256 + lane * 4, bufA + i * 256);
    #pragma unroll
    for (int i = 0; i < 2; i++) stage16(wu + (4 + i) * 256 + lane * 4, bufA + 512 + i * 256);
    // ---- section 1 (B); prefetch section 3 into B
    asm volatile("s_waitcnt vmcnt(4)" ::: "memory"); // S1 done, S2 outstanding
    #pragma unroll
    for (int i = 0; i < 2; i++) {
        float4 gv = *reinterpret_cast<float4*>(bufB + i * 256 + lane * 4);
        float4 uv = *reinterpret_cast<float4*>(bufB + 512 + i * 256 + lane * 4);
        float4 x4 = xv[1 * 2 + i];
        ag = fmaf(gv.x, x4.x, fmaf(gv.y, x4.y, fmaf(gv.z, x4.z, fmaf(gv.w, x4.w, ag))));
        au = fmaf(uv.x, x4.x, fmaf(uv.y, x4.y, fmaf(uv.z, x4.z, fmaf(uv.w, x4.w, au))));
    }
    #pragma unroll
    for (int i = 0; i < 2; i++) stage16(wg + (6 + i) * 256 + lane * 4, bufB + i * 256);
    #pragma unroll
    for (int i = 0; i < 2; i++) stage16(wu + (6 + i) * 256 + lane * 4, bufB + 512 + i * 256);
    // ---- section 2 (A)
    asm volatile("s_waitcnt vmcnt(4)" ::: "memory"); // S2 done, S3 outstanding
    #pragma unroll
    for (int i = 0; i < 2; i++) {
        float4 gv = *reinterpret_cast<float4*>(bufA + i * 256 + lane * 4);
        float4 uv = *reinterpret_cast<float4*>(bufA + 512 + i * 256 + lane * 4);
        float4 x4 = xv[2 * 2 + i];
        ag = fmaf(gv.x, x4.x, fmaf(gv.y, x4.y, fmaf(gv.z, x4.z, fmaf(gv.w, x4.w, ag))));
        au = fmaf(uv.x, x4.x, fmaf(uv.y, x4.y, fmaf(uv.z, x4.z, fmaf(uv.w, x4.w, au))));
    }
    // ---- section 3 (B)
    asm volatile("s_waitcnt vmcnt(0)" ::: "memory");
    #pragma unroll
    for (int i = 0; i < 2; i++) {
        float4 gv = *reinterpret_cast<float4*>(bufB + i * 256 + lane * 4);
        float4 uv = *reinterpret_cast<float4*>(bufB + 512 + i * 256 + lane * 4);
        float4 x4 = xv[3 * 2 + i];
        ag = fmaf(gv.x, x4.x, fmaf(gv.y, x4.y, fmaf(gv.z, x4.z, fmaf(gv.w, x4.w, ag))));
        au = fmaf(uv.x, x4.x, fmaf(uv.y, x4.y, fmaf(uv.z, x4.z, fmaf(uv.w, x4.w, au))));
    }
    ag = warp_sum(ag);
    au = warp_sum(au);
    if (lane == 0) act[row] = gelu_tanh(ag) * au;
}

// ---------- Wdown GEMV (2048 rows x 8192), double-buffered quarters ----------
__global__ void down_lds(const float* __restrict__ Wd, const float* __restrict__ act,
                         float* __restrict__ y) {
    __shared__ float smem[4 * 4096]; // 16 KB/wave: A(2048 floats) + B(2048 floats) = 64 KB/block
    int lane = threadIdx.x & 63, wid = threadIdx.x >> 6;
    int row = blockIdx.x * 4 + wid; // 0..2047
    float* bufA = smem + wid * 4096;
    float* bufB = bufA + 2048;
    const float* wr = Wd + (size_t)row * DFF;
    float4 av[8];
    float acc = 0.f;
    // S0 -> A
    #pragma unroll
    for (int c = 0; c < 8; c++) stage16(wr + c * 256 + lane * 4, bufA + c * 256);
    // A0 (act quarter 0)
    #pragma unroll
    for (int c = 0; c < 8; c++) av[c] = *reinterpret_cast<const float4*>(act + c * 256 + lane * 4);
    // S1 -> B
    #pragma unroll
    for (int c = 0; c < 8; c++) stage16(wr + 2048 + c * 256 + lane * 4, bufB + c * 256);
    // ---- q0: S0+A0 done (S1 outstanding)
    asm volatile("s_waitcnt vmcnt(8)" ::: "memory");
    #pragma unroll
    for (int c = 0; c < 8; c++) {
        float4 wv = *reinterpret_cast<float4*>(bufA + c * 256 + lane * 4);
        acc = fmaf(wv.x, av[c].x, fmaf(wv.y, av[c].y, fmaf(wv.z, av[c].z, fmaf(wv.w, av[c].w, acc))));
    }
    // A1, S2 -> A
    #pragma unroll
    for (int c = 0; c < 8; c++) av[c] = *reinterpret_cast<const float4*>(act + 2048 + c * 256 + lane * 4);
    #pragma unroll
    for (int c = 0; c < 8; c++) stage16(wr + 4096 + c * 256 + lane * 4, bufA + c * 256);
    // ---- q1: S1+A1 done (S2 outstanding)
    asm volatile("s_waitcnt vmcnt(8)" ::: "memory");
    #pragma unroll
    for (int c = 0; c < 8; c++) {
        float4 wv = *reinterpret_cast<float4*>(bufB + c * 256 + lane * 4);
        acc = fmaf(wv.x, av[c].x, fmaf(wv.y, av[c].y, fmaf(wv.z, av[c].z, fmaf(wv.w, av[c].w, acc))));
    }
    // A2, S3 -> B
    #pragma unroll
    for (int c = 0; c < 8; c++) av[c] = *reinterpret_cast<const float4*>(act + 4096 + c * 256 + lane * 4);
    #pragma unroll
    for (int c = 0; c < 8; c++) stage16(wr + 6144 + c * 256 + lane * 4, bufB + c * 256);
    // ---- q2: S2+A2 done (S3 outstanding)
    asm volatile("s_waitcnt vmcnt(8)" ::: "memory");
    #pragma unroll
    for (int c = 0; c < 8; c++) {
        float4 wv = *reinterpret_cast<float4*>(bufA + c * 256 + lane * 4);
        acc = fmaf(wv.x, av[c].x, fmaf(wv.y, av[c].y, fmaf(wv.z, av[c].z, fmaf(wv.w, av[c].w, acc))));
    }
    // A3
    #pragma unroll
    for (int c = 0; c < 8; c++) av[c] = *reinterpret_cast<const float4*>(act + 6144 + c * 256 + lane * 4);
    // ---- q3: everything done
    asm volatile("s_waitcnt vmcnt(0)" ::: "memory");
    #pragma unroll
    for (int c = 0; c < 8; c++) {
        float4 wv = *reinterpret_cast<float4*>(bufB + c * 256 + lane * 4);
        acc = fmaf(wv.x, av[c].x, fmaf(wv.y, av[c].y, fmaf(wv.z, av[c].z, fmaf(wv.w, av[c].w, acc))));
    }
    acc = warp_sum(acc);
    if (lane == 0) y[row] = acc;
}

// ---------- per-head rmsnorm + RoPE (q,k) / weightless rmsnorm (v) ----------
__global__ void head_norm_rope(const float* __restrict__ qraw, const float* __restrict__ kraw,
                               const float* __restrict__ vraw, const float* __restrict__ qw,
                               const float* __restrict__ kw, const float* __restrict__ cosv,
                               const float* __restrict__ sinv, float* __restrict__ qf,
                               float* __restrict__ kf, float* __restrict__ vf) {
    __shared__ float s4[4];
    __shared__ float sn[HD];
    int b = blockIdx.x, t = threadIdx.x;
    const float* in; float* out; const float* w; bool rope;
    if (b < 8)       { in = qraw + b * HD;        out = qf + b * HD;        w = qw;      rope = true;  }
    else if (b < 10) { in = kraw + (b - 8) * HD;  out = kf + (b - 8) * HD;  w = kw;      rope = true;  }
    else             { in = vraw + (b - 10) * HD; out = vf + (b - 10) * HD; w = nullptr; rope = false; }
    float x = in[t];
    float tot = block_sum256(x * x, s4);
    float rs = rsqrtf(tot / (float)HD + EPS);
    float nv = x * rs * (w ? (1.f + w[t]) : 1.f);
    sn[t] = nv;
    __syncthreads();
    float o = nv;
    if (rope) {
        float rh = (t < HD / 2) ? -sn[t + HD / 2] : sn[t - HD / 2];
        o = nv * cosv[t] + rh * sinv[t];
    }
    out[t] = o;
}

// ---------- attention scores ----------
__global__ void attn_scores(const float* __restrict__ kvc, const float* __restrict__ kf,
                            const float* __restrict__ mask, const float* __restrict__ qf,
                            const int* __restrict__ ring_p, float* __restrict__ scores) {
    int head = blockIdx.x >> 3, wc = blockIdx.x & 7;
    int kvh = head >> 2; // n_rep = 4
    int lane = threadIdx.x & 63, wid = threadIdx.x >> 6;
    int ring = *ring_p;
    float4 qv = *reinterpret_cast<const float4*>(qf + head * HD + lane * 4);
    const float* Kbase = kvc + (size_t)kvh * W * HD;
    #pragma unroll 4
    for (int i = 0; i < 16; i++) {
        int w = wc * 64 + wid * 16 + i;
        const float* krow = (w == ring) ? (kf + kvh * HD) : (Kbase + (size_t)w * HD);
        float4 kv4 = *reinterpret_cast<const float4*>(krow + lane * 4);
        float acc = qv.x * kv4.x + qv.y * kv4.y + qv.z * kv4.z + qv.w * kv4.w;
        acc = warp_sum(acc);
        if (lane == 0) scores[head * W + w] = acc + mask[w];
    }
}

// ---------- softmax per head + zero attn_o ----------
__global__ void attn_softmax(float* __restrict__ scores, float* __restrict__ attn_o) {
    __shared__ float s4[4];
    int head = blockIdx.x, t = threadIdx.x;
    float s0 = scores[head * W + t], s1 = scores[head * W + 256 + t];
    float m = block_max256(fmaxf(s0, s1), s4);
    float e0 = expf(s0 - m), e1 = expf(s1 - m);
    float sum = block_sum256(e0 + e1, s4);
    float inv = 1.f / sum;
    scores[head * W + t] = e0 * inv;
    scores[head * W + 256 + t] = e1 * inv;
    attn_o[head * HD + t] = 0.f;
}

// ---------- o partials ----------
__global__ void attn_o_partial(const float* __restrict__ kvc, const float* __restrict__ vf,
                               const float* __restrict__ p, const int* __restrict__ ring_p,
                               float* __restrict__ attn_o) {
    int head = blockIdx.x >> 3, wc = blockIdx.x & 7;
    int kvh = head >> 2;
    int d = threadIdx.x;
    int ring = *ring_p;
    const float* Vbase = kvc + (size_t)(NKV + kvh) * W * HD;
    float acc = 0.f;
    #pragma unroll 4
    for (int i = 0; i < 64; i++) {
        int w = wc * 64 + i;
        float pw = p[head * W + w];
        const float* vrow = (w == ring) ? (vf + kvh * HD) : (Vbase + (size_t)w * HD);
        acc = fmaf(pw, vrow[d], acc);
    }
    atomicAdd(&attn_o[head * HD + d], acc);
}

// ---------- register GEMV for tiny 256-col plproj ----------
template <int NC>
__global__ void gemv(const float* __restrict__ Wm, const float* __restrict__ x,
                     float* __restrict__ y) {
    int lane = threadIdx.x & 63, wid = threadIdx.x >> 6;
    int row = blockIdx.x * 4 + wid;
    const float* wr = Wm + (size_t)row * NC;
    float acc = 0.f;
    #pragma unroll
    for (int it = 0; it < NC / 256; it++) {
        int c = it * 256 + lane * 4;
        float4 wv = *reinterpret_cast<const float4*>(wr + c);
        float4 xv = *reinterpret_cast<const float4*>(x + c);
        acc = fmaf(wv.x, xv.x, fmaf(wv.y, xv.y, fmaf(wv.z, xv.z, fmaf(wv.w, xv.w, acc))));
    }
    acc = warp_sum(acc);
    if (lane == 0) y[row] = acc;
}

// ---------- x1 = res + rmsnorm(y, w1); hn = rmsnorm(x1, w2) ----------
__global__ void post_attn_fused(const float* __restrict__ res, const float* __restrict__ y,
                                const float* __restrict__ w1, const float* __restrict__ w2,
                                float* __restrict__ x1, float* __restrict__ hn) {
    __shared__ float s4[4];
    int t = threadIdx.x;
    float yv[8], ss = 0.f;
    #pragma unroll
    for (int i = 0; i < 8; i++) { yv[i] = y[t + i * 256]; ss += yv[i] * yv[i]; }
    float tot = block_sum256(ss, s4);
    float rs = rsqrtf(tot / (float)D + EPS);
    float xv[8]; ss = 0.f;
    #pragma unroll
    for (int i = 0; i < 8; i++) {
        int idx = t + i * 256;
        float v = res[idx] + yv[i] * rs * (1.f + w1[idx]);
        xv[i] = v; x1[idx] = v; ss += v * v;
    }
    tot = block_sum256(ss, s4);
    rs = rsqrtf(tot / (float)D + EPS);
    #pragma unroll
    for (int i = 0; i < 8; i++) {
        int idx = t + i * 256;
        hn[idx] = xv[i] * rs * (1.f + w2[idx]);
    }
}

// ---------- x2 = res + rmsnorm(y, w) ----------
__global__ void residual_rms(const float* __restrict__ res, const float* __restrict__ y,
                             const float* __restrict__ w, float* __restrict__ out) {
    __shared__ float s4[4];
    int t = threadIdx.x;
    float yv[8], ss = 0.f;
    #pragma unroll
    for (int i = 0; i < 8; i++) { yv[i] = y[t + i * 256]; ss += yv[i] * yv[i]; }
    float tot = block_sum256(ss, s4);
    float rs = rsqrtf(tot / (float)D + EPS);
    #pragma unroll
    for (int i = 0; i < 8; i++) {
        int idx = t + i * 256;
        out[idx] = res[idx] + yv[i] * rs * (1.f + w[idx]);
    }
}

// ---------- out = (x2 + rmsnorm(g2, w)) * layer_scalar ----------
__global__ void final_kernel(const float* __restrict__ x2, const float* __restrict__ g2,
                             const float* __restrict__ w, const float* __restrict__ scal,
                             float* __restrict__ out) {
    __shared__ float s4[4];
    int t = threadIdx.x;
    float gv[8], ss = 0.f;
    #pragma unroll
    for (int i = 0; i < 8; i++) { gv[i] = g2[t + i * 256]; ss += gv[i] * gv[i]; }
    float tot = block_sum256(ss, s4);
    float rs = rsqrtf(tot / (float)D + EPS);
    float sc = scal[0];
    #pragma unroll
    for (int i = 0; i < 8; i++) {
        int idx = t + i * 256;
        out[idx] = (x2[idx] + gv[i] * rs * (1.f + w[idx])) * sc;
    }
}

extern "C" void kernel_launch(void* const* d_in, const int* in_sizes, int n_in,
                              void* d_out, int out_size, void* d_ws, size_t ws_size,
                              hipStream_t stream) {
    const float* x_in        = (const float*)d_in[0];
    const float* cosv        = (const float*)d_in[1];
    const float* sinv        = (const float*)d_in[2];
    const float* mask        = (const float*)d_in[3];
    const float* kvc         = (const float*)d_in[4];
    const float* per_layer   = (const float*)d_in[5];
    const float* ln_in_w     = (const float*)d_in[6];
    const float* Wq          = (const float*)d_in[7];
    const float* q_norm_w    = (const float*)d_in[8];
    const float* Wk          = (const float*)d_in[9];
    const float* Wv          = (const float*)d_in[10];
    const float* k_norm_w    = (const float*)d_in[11];
    const float* Wo          = (const float*)d_in[12];
    const float* post_attn_w = (const float*)d_in[13];
    const float* pre_ffn_w   = (const float*)d_in[14];
    const float* Wgate       = (const float*)d_in[15];
    const float* Wup         = (const float*)d_in[16];
    const float* Wdown       = (const float*)d_in[17];
    const float* post_ffn_w  = (const float*)d_in[18];
    const float* Wpl_gate    = (const float*)d_in[19];
    const float* Wpl_proj    = (const float*)d_in[20];
    const float* post_pl_w   = (const float*)d_in[21];
    const float* layer_scal  = (const float*)d_in[22];
    const int*   ring_pos    = (const int*)d_in[23];
    float* out = (float*)d_out;
    float* ws  = (float*)d_ws;

    float* h      = ws;          // 2048
    float* qraw   = ws + 2048;   // 2048
    float* kraw   = ws + 4096;   // 512
    float* vraw   = ws + 4608;   // 512
    float* qf     = ws + 5120;   // 2048
    float* kf     = ws + 7168;   // 512
    float* vf     = ws + 7680;   // 512
    float* scores = ws + 8192;   // 8*512
    float* attn_o = ws + 12288;  // 2048
    float* y_wo   = ws + 14336;  // 2048
    float* x1     = ws + 16384;  // 2048
    float* hn     = ws + 18432;  // 2048
    float* act    = ws + 20480;  // 8192
    float* y2     = ws + 28672;  // 2048
    float* x2     = ws + 30720;  // 2048
    float* g      = ws + 32768;  // 256
    float* g2     = ws + 33024;  // 2048

    rms_in_kernel<<<1, 256, 0, stream>>>(x_in, ln_in_w, h);
    gemv_qkv_lds<<<768, 256, 0, stream>>>(Wq, Wk, Wv, h, qraw, kraw, vraw);
    head_norm_rope<<<12, 256, 0, stream>>>(qraw, kraw, vraw, q_norm_w, k_norm_w,
                                           cosv, sinv, qf, kf, vf);
    attn_scores<<<64, 256, 0, stream>>>(kvc, kf, mask, qf, ring_pos, scores);
    attn_softmax<<<8, 256, 0, stream>>>(scores, attn_o);
    attn_o_partial<<<64, 256, 0, stream>>>(kvc, vf, scores, ring_pos, attn_o);
    gemv2048_lds<0><<<512, 256, 0, stream>>>(Wo, attn_o, nullptr, y_wo);
    post_attn_fused<<<1, 256, 0, stream>>>(x_in, y_wo, post_attn_w, pre_ffn_w, x1, hn);
    gateup_lds<<<2048, 256, 0, stream>>>(Wgate, Wup, hn, act);
    down_lds<<<512, 256, 0, stream>>>(Wdown, act, y2);
    residual_rms<<<1, 256, 0, stream>>>(x1, y2, post_ffn_w, x2);
    gemv2048_lds<1><<<64, 256, 0, stream>>>(Wpl_gate, x2, per_layer, g);
    gemv<256><<<512, 256, 0, stream>>>(Wpl_proj, g, g2);
    final_kernel<<<1, 256, 0, stream>>>(x2, g2, post_pl_w, layer_scal, out);
}

// Round 3
// 77.474 us; speedup vs baseline: 1.0731x; 1.0731x over previous
//
#include <hip/hip_runtime.h>
#include <math.h>

// Dims
#define D 2048
#define NH 8
#define NKV 2
#define HD 256
#define DFF 8192
#define W 512
#define PLD 256
#define EPS 1e-6f

typedef float f32x4 __attribute__((ext_vector_type(4)));

__device__ __forceinline__ f32x4 ntld(const float* p) {
    return __builtin_nontemporal_load(reinterpret_cast<const f32x4*>(p));
}
__device__ __forceinline__ f32x4 ld4(const float* p) {
    return *reinterpret_cast<const f32x4*>(p);
}
__device__ __forceinline__ float dot4(f32x4 a, f32x4 b, float acc) {
    return fmaf(a.x, b.x, fmaf(a.y, b.y, fmaf(a.z, b.z, fmaf(a.w, b.w, acc))));
}

__device__ __forceinline__ float warp_sum(float v) {
    #pragma unroll
    for (int off = 32; off > 0; off >>= 1) v += __shfl_down(v, off, 64);
    return v;
}
__device__ __forceinline__ float warp_max(float v) {
    #pragma unroll
    for (int off = 32; off > 0; off >>= 1) v = fmaxf(v, __shfl_down(v, off, 64));
    return v;
}

// block of 256 threads = 4 waves
__device__ __forceinline__ float block_sum256(float v, float* s4) {
    int lane = threadIdx.x & 63, wid = threadIdx.x >> 6;
    v = warp_sum(v);
    if (lane == 0) s4[wid] = v;
    __syncthreads();
    float r = s4[0] + s4[1] + s4[2] + s4[3];
    __syncthreads();
    return r;
}
__device__ __forceinline__ float block_max256(float v, float* s4) {
    int lane = threadIdx.x & 63, wid = threadIdx.x >> 6;
    v = warp_max(v);
    if (lane == 0) s4[wid] = v;
    __syncthreads();
    float r = fmaxf(fmaxf(s4[0], s4[1]), fmaxf(s4[2], s4[3]));
    __syncthreads();
    return r;
}

__device__ __forceinline__ float gelu_tanh(float x) {
    const float c = 0.7978845608028654f; // sqrt(2/pi)
    float t = tanhf(c * (x + 0.044715f * x * x * x));
    return 0.5f * x * (1.0f + t);
}

// ---------- h = rmsnorm(x, w) over D, 1 block x 256 ----------
__global__ void rms_in_kernel(const float* __restrict__ x, const float* __restrict__ w,
                              float* __restrict__ out) {
    __shared__ float s4[4];
    int t = threadIdx.x;
    float v[8], ss = 0.f;
    #pragma unroll
    for (int i = 0; i < 8; i++) { v[i] = x[t + i * 256]; ss += v[i] * v[i]; }
    float tot = block_sum256(ss, s4);
    float rs = rsqrtf(tot / (float)D + EPS);
    #pragma unroll
    for (int i = 0; i < 8; i++) out[t + i * 256] = v[i] * rs * (1.f + w[t + i * 256]);
}

// ---------- fused q/k/v projection: 3072 rows x 2048, NT weight loads ----------
__global__ void gemv_qkv_nt(const float* __restrict__ Wq, const float* __restrict__ Wk,
                            const float* __restrict__ Wv, const float* __restrict__ h,
                            float* __restrict__ qraw, float* __restrict__ kraw,
                            float* __restrict__ vraw) {
    int lane = threadIdx.x & 63, wid = threadIdx.x >> 6;
    int row = blockIdx.x * 4 + wid; // 0..3071
    const float* wr;
    float* out;
    if (row < 2048)      { wr = Wq + (size_t)row * D;          out = qraw + row; }
    else if (row < 2560) { wr = Wk + (size_t)(row - 2048) * D; out = kraw + (row - 2048); }
    else                 { wr = Wv + (size_t)(row - 2560) * D; out = vraw + (row - 2560); }
    f32x4 w[8], xv[8];
    #pragma unroll
    for (int c = 0; c < 8; c++) w[c] = ntld(wr + c * 256 + lane * 4);
    #pragma unroll
    for (int c = 0; c < 8; c++) xv[c] = ld4(h + c * 256 + lane * 4);
    float acc = 0.f;
    #pragma unroll
    for (int c = 0; c < 8; c++) acc = dot4(w[c], xv[c], acc);
    acc = warp_sum(acc);
    if (lane == 0) *out = acc;
}

// ---------- generic 2048-col GEMV, NT weights. MODE 0: plain; 1: gelu(acc)*aux ----------
template <int MODE>
__global__ void gemv2048_nt(const float* __restrict__ Wm, const float* __restrict__ x,
                            const float* __restrict__ aux, float* __restrict__ y) {
    int lane = threadIdx.x & 63, wid = threadIdx.x >> 6;
    int row = blockIdx.x * 4 + wid;
    const float* wr = Wm + (size_t)row * D;
    f32x4 w[8], xv[8];
    #pragma unroll
    for (int c = 0; c < 8; c++) w[c] = ntld(wr + c * 256 + lane * 4);
    #pragma unroll
    for (int c = 0; c < 8; c++) xv[c] = ld4(x + c * 256 + lane * 4);
    float acc = 0.f;
    #pragma unroll
    for (int c = 0; c < 8; c++) acc = dot4(w[c], xv[c], acc);
    acc = warp_sum(acc);
    if (lane == 0) {
        if (MODE == 0) y[row] = acc;
        else           y[row] = gelu_tanh(acc) * aux[row];
    }
}

// ---------- fused gate/up GEMV: both rows fully in registers, NT ----------
__global__ void gateup_nt(const float* __restrict__ Wg, const float* __restrict__ Wu,
                          const float* __restrict__ hn, float* __restrict__ act) {
    int lane = threadIdx.x & 63, wid = threadIdx.x >> 6;
    int row = blockIdx.x * 4 + wid; // 0..8191
    const float* wg = Wg + (size_t)row * D;
    const float* wu = Wu + (size_t)row * D;
    f32x4 g[8], u[8], xv[8];
    #pragma unroll
    for (int c = 0; c < 8; c++) g[c] = ntld(wg + c * 256 + lane * 4);
    #pragma unroll
    for (int c = 0; c < 8; c++) u[c] = ntld(wu + c * 256 + lane * 4);
    #pragma unroll
    for (int c = 0; c < 8; c++) xv[c] = ld4(hn + c * 256 + lane * 4);
    float ag = 0.f, au = 0.f;
    #pragma unroll
    for (int c = 0; c < 8; c++) { ag = dot4(g[c], xv[c], ag); au = dot4(u[c], xv[c], au); }
    ag = warp_sum(ag);
    au = warp_sum(au);
    if (lane == 0) act[row] = gelu_tanh(ag) * au;
}

// ---------- Wdown GEMV (2048 rows x 8192), ping-pong register sections, NT ----------
__global__ void down_nt(const float* __restrict__ Wd, const float* __restrict__ act,
                        float* __restrict__ y) {
    int lane = threadIdx.x & 63, wid = threadIdx.x >> 6;
    int row = blockIdx.x * 4 + wid; // 0..2047
    const float* wr = Wd + (size_t)row * DFF;
    f32x4 wA[8], wB[8], a[8];
    float acc = 0.f;
    #pragma unroll
    for (int c = 0; c < 8; c++) wA[c] = ntld(wr + c * 256 + lane * 4);
    #pragma unroll
    for (int c = 0; c < 8; c++) wB[c] = ntld(wr + 2048 + c * 256 + lane * 4);
    // q0 (A); prefetch q2 -> A
    #pragma unroll
    for (int c = 0; c < 8; c++) a[c] = ld4(act + c * 256 + lane * 4);
    #pragma unroll
    for (int c = 0; c < 8; c++) acc = dot4(wA[c], a[c], acc);
    #pragma unroll
    for (int c = 0; c < 8; c++) wA[c] = ntld(wr + 4096 + c * 256 + lane * 4);
    // q1 (B); prefetch q3 -> B
    #pragma unroll
    for (int c = 0; c < 8; c++) a[c] = ld4(act + 2048 + c * 256 + lane * 4);
    #pragma unroll
    for (int c = 0; c < 8; c++) acc = dot4(wB[c], a[c], acc);
    #pragma unroll
    for (int c = 0; c < 8; c++) wB[c] = ntld(wr + 6144 + c * 256 + lane * 4);
    // q2 (A)
    #pragma unroll
    for (int c = 0; c < 8; c++) a[c] = ld4(act + 4096 + c * 256 + lane * 4);
    #pragma unroll
    for (int c = 0; c < 8; c++) acc = dot4(wA[c], a[c], acc);
    // q3 (B)
    #pragma unroll
    for (int c = 0; c < 8; c++) a[c] = ld4(act + 6144 + c * 256 + lane * 4);
    #pragma unroll
    for (int c = 0; c < 8; c++) acc = dot4(wB[c], a[c], acc);
    acc = warp_sum(acc);
    if (lane == 0) y[row] = acc;
}

// ---------- tiny 256-col GEMV (plproj), NT ----------
__global__ void gemv256_nt(const float* __restrict__ Wm, const float* __restrict__ x,
                           float* __restrict__ y) {
    int lane = threadIdx.x & 63, wid = threadIdx.x >> 6;
    int row = blockIdx.x * 4 + wid;
    const float* wr = Wm + (size_t)row * PLD;
    f32x4 w0 = ntld(wr + lane * 4);
    f32x4 x0 = ld4(x + lane * 4);
    float acc = dot4(w0, x0, 0.f);
    acc = warp_sum(acc);
    if (lane == 0) y[row] = acc;
}

// ---------- per-head rmsnorm + RoPE (q,k) / weightless rmsnorm (v) ----------
__global__ void head_norm_rope(const float* __restrict__ qraw, const float* __restrict__ kraw,
                               const float* __restrict__ vraw, const float* __restrict__ qw,
                               const float* __restrict__ kw, const float* __restrict__ cosv,
                               const float* __restrict__ sinv, float* __restrict__ qf,
                               float* __restrict__ kf, float* __restrict__ vf) {
    __shared__ float s4[4];
    __shared__ float sn[HD];
    int b = blockIdx.x, t = threadIdx.x;
    const float* in; float* out; const float* w; bool rope;
    if (b < 8)       { in = qraw + b * HD;        out = qf + b * HD;        w = qw;      rope = true;  }
    else if (b < 10) { in = kraw + (b - 8) * HD;  out = kf + (b - 8) * HD;  w = kw;      rope = true;  }
    else             { in = vraw + (b - 10) * HD; out = vf + (b - 10) * HD; w = nullptr; rope = false; }
    float x = in[t];
    float tot = block_sum256(x * x, s4);
    float rs = rsqrtf(tot / (float)HD + EPS);
    float nv = x * rs * (w ? (1.f + w[t]) : 1.f);
    sn[t] = nv;
    __syncthreads();
    float o = nv;
    if (rope) {
        float rh = (t < HD / 2) ? -sn[t + HD / 2] : sn[t - HD / 2];
        o = nv * cosv[t] + rh * sinv[t];
    }
    out[t] = o;
}

// ---------- attention scores ----------
__global__ void attn_scores(const float* __restrict__ kvc, const float* __restrict__ kf,
                            const float* __restrict__ mask, const float* __restrict__ qf,
                            const int* __restrict__ ring_p, float* __restrict__ scores) {
    int head = blockIdx.x >> 3, wc = blockIdx.x & 7;
    int kvh = head >> 2; // n_rep = 4
    int lane = threadIdx.x & 63, wid = threadIdx.x >> 6;
    int ring = *ring_p;
    f32x4 qv = ld4(qf + head * HD + lane * 4);
    const float* Kbase = kvc + (size_t)kvh * W * HD;
    #pragma unroll 4
    for (int i = 0; i < 16; i++) {
        int w = wc * 64 + wid * 16 + i;
        const float* krow = (w == ring) ? (kf + kvh * HD) : (Kbase + (size_t)w * HD);
        f32x4 kv4 = ld4(krow + lane * 4);
        float acc = dot4(qv, kv4, 0.f);
        acc = warp_sum(acc);
        if (lane == 0) scores[head * W + w] = acc + mask[w];
    }
}

// ---------- softmax per head + zero attn_o ----------
__global__ void attn_softmax(float* __restrict__ scores, float* __restrict__ attn_o) {
    __shared__ float s4[4];
    int head = blockIdx.x, t = threadIdx.x;
    float s0 = scores[head * W + t], s1 = scores[head * W + 256 + t];
    float m = block_max256(fmaxf(s0, s1), s4);
    float e0 = expf(s0 - m), e1 = expf(s1 - m);
    float sum = block_sum256(e0 + e1, s4);
    float inv = 1.f / sum;
    scores[head * W + t] = e0 * inv;
    scores[head * W + 256 + t] = e1 * inv;
    attn_o[head * HD + t] = 0.f;
}

// ---------- o partials ----------
__global__ void attn_o_partial(const float* __restrict__ kvc, const float* __restrict__ vf,
                               const float* __restrict__ p, const int* __restrict__ ring_p,
                               float* __restrict__ attn_o) {
    int head = blockIdx.x >> 3, wc = blockIdx.x & 7;
    int kvh = head >> 2;
    int d = threadIdx.x;
    int ring = *ring_p;
    const float* Vbase = kvc + (size_t)(NKV + kvh) * W * HD;
    float acc = 0.f;
    #pragma unroll 4
    for (int i = 0; i < 64; i++) {
        int w = wc * 64 + i;
        float pw = p[head * W + w];
        const float* vrow = (w == ring) ? (vf + kvh * HD) : (Vbase + (size_t)w * HD);
        acc = fmaf(pw, vrow[d], acc);
    }
    atomicAdd(&attn_o[head * HD + d], acc);
}

// ---------- x1 = res + rmsnorm(y, w1); hn = rmsnorm(x1, w2) ----------
__global__ void post_attn_fused(const float* __restrict__ res, const float* __restrict__ y,
                                const float* __restrict__ w1, const float* __restrict__ w2,
                                float* __restrict__ x1, float* __restrict__ hn) {
    __shared__ float s4[4];
    int t = threadIdx.x;
    float yv[8], ss = 0.f;
    #pragma unroll
    for (int i = 0; i < 8; i++) { yv[i] = y[t + i * 256]; ss += yv[i] * yv[i]; }
    float tot = block_sum256(ss, s4);
    float rs = rsqrtf(tot / (float)D + EPS);
    float xv[8]; ss = 0.f;
    #pragma unroll
    for (int i = 0; i < 8; i++) {
        int idx = t + i * 256;
        float v = res[idx] + yv[i] * rs * (1.f + w1[idx]);
        xv[i] = v; x1[idx] = v; ss += v * v;
    }
    tot = block_sum256(ss, s4);
    rs = rsqrtf(tot / (float)D + EPS);
    #pragma unroll
    for (int i = 0; i < 8; i++) {
        int idx = t + i * 256;
        hn[idx] = xv[i] * rs * (1.f + w2[idx]);
    }
}

// ---------- x2 = res + rmsnorm(y, w) ----------
__global__ void residual_rms(const float* __restrict__ res, const float* __restrict__ y,
                             const float* __restrict__ w, float* __restrict__ out) {
    __shared__ float s4[4];
    int t = threadIdx.x;
    float yv[8], ss = 0.f;
    #pragma unroll
    for (int i = 0; i < 8; i++) { yv[i] = y[t + i * 256]; ss += yv[i] * yv[i]; }
    float tot = block_sum256(ss, s4);
    float rs = rsqrtf(tot / (float)D + EPS);
    #pragma unroll
    for (int i = 0; i < 8; i++) {
        int idx = t + i * 256;
        out[idx] = res[idx] + yv[i] * rs * (1.f + w[idx]);
    }
}

// ---------- out = (x2 + rmsnorm(g2, w)) * layer_scalar ----------
__global__ void final_kernel(const float* __restrict__ x2, const float* __restrict__ g2,
                             const float* __restrict__ w, const float* __restrict__ scal,
                             float* __restrict__ out) {
    __shared__ float s4[4];
    int t = threadIdx.x;
    float gv[8], ss = 0.f;
    #pragma unroll
    for (int i = 0; i < 8; i++) { gv[i] = g2[t + i * 256]; ss += gv[i] * gv[i]; }
    float tot = block_sum256(ss, s4);
    float rs = rsqrtf(tot / (float)D + EPS);
    float sc = scal[0];
    #pragma unroll
    for (int i = 0; i < 8; i++) {
        int idx = t + i * 256;
        out[idx] = (x2[idx] + gv[i] * rs * (1.f + w[idx])) * sc;
    }
}

extern "C" void kernel_launch(void* const* d_in, const int* in_sizes, int n_in,
                              void* d_out, int out_size, void* d_ws, size_t ws_size,
                              hipStream_t stream) {
    const float* x_in        = (const float*)d_in[0];
    const float* cosv        = (const float*)d_in[1];
    const float* sinv        = (const float*)d_in[2];
    const float* mask        = (const float*)d_in[3];
    const float* kvc         = (const float*)d_in[4];
    const float* per_layer   = (const float*)d_in[5];
    const float* ln_in_w     = (const float*)d_in[6];
    const float* Wq          = (const float*)d_in[7];
    const float* q_norm_w    = (const float*)d_in[8];
    const float* Wk          = (const float*)d_in[9];
    const float* Wv          = (const float*)d_in[10];
    const float* k_norm_w    = (const float*)d_in[11];
    const float* Wo          = (const float*)d_in[12];
    const float* post_attn_w = (const float*)d_in[13];
    const float* pre_ffn_w   = (const float*)d_in[14];
    const float* Wgate       = (const float*)d_in[15];
    const float* Wup         = (const float*)d_in[16];
    const float* Wdown       = (const float*)d_in[17];
    const float* post_ffn_w  = (const float*)d_in[18];
    const float* Wpl_gate    = (const float*)d_in[19];
    const float* Wpl_proj    = (const float*)d_in[20];
    const float* post_pl_w   = (const float*)d_in[21];
    const float* layer_scal  = (const float*)d_in[22];
    const int*   ring_pos    = (const int*)d_in[23];
    float* out = (float*)d_out;
    float* ws  = (float*)d_ws;

    float* h      = ws;          // 2048
    float* qraw   = ws + 2048;   // 2048
    float* kraw   = ws + 4096;   // 512
    float* vraw   = ws + 4608;   // 512
    float* qf     = ws + 5120;   // 2048
    float* kf     = ws + 7168;   // 512
    float* vf     = ws + 7680;   // 512
    float* scores = ws + 8192;   // 8*512
    float* attn_o = ws + 12288;  // 2048
    float* y_wo   = ws + 14336;  // 2048
    float* x1     = ws + 16384;  // 2048
    float* hn     = ws + 18432;  // 2048
    float* act    = ws + 20480;  // 8192
    float* y2     = ws + 28672;  // 2048
    float* x2     = ws + 30720;  // 2048
    float* g      = ws + 32768;  // 256
    float* g2     = ws + 33024;  // 2048

    rms_in_kernel<<<1, 256, 0, stream>>>(x_in, ln_in_w, h);
    gemv_qkv_nt<<<768, 256, 0, stream>>>(Wq, Wk, Wv, h, qraw, kraw, vraw);
    head_norm_rope<<<12, 256, 0, stream>>>(qraw, kraw, vraw, q_norm_w, k_norm_w,
                                           cosv, sinv, qf, kf, vf);
    attn_scores<<<64, 256, 0, stream>>>(kvc, kf, mask, qf, ring_pos, scores);
    attn_softmax<<<8, 256, 0, stream>>>(scores, attn_o);
    attn_o_partial<<<64, 256, 0, stream>>>(kvc, vf, scores, ring_pos, attn_o);
    gemv2048_nt<0><<<512, 256, 0, stream>>>(Wo, attn_o, nullptr, y_wo);
    post_attn_fused<<<1, 256, 0, stream>>>(x_in, y_wo, post_attn_w, pre_ffn_w, x1, hn);
    gateup_nt<<<2048, 256, 0, stream>>>(Wgate, Wup, hn, act);
    down_nt<<<512, 256, 0, stream>>>(Wdown, act, y2);
    residual_rms<<<1, 256, 0, stream>>>(x1, y2, post_ffn_w, x2);
    gemv2048_nt<1><<<64, 256, 0, stream>>>(Wpl_gate, x2, per_layer, g);
    gemv256_nt<<<512, 256, 0, stream>>>(Wpl_proj, g, g2);
    final_kernel<<<1, 256, 0, stream>>>(x2, g2, post_pl_w, layer_scal, out);
}